// Round 1
// baseline (3981.458 us; speedup 1.0000x reference)
//
#include <hip/hip_runtime.h>

#define NN 512
#define NM1 511

// One block per matrix. 1024 threads: thread (tr = tid&255, tc = tid>>8)
// owns row tr, columns [tc*64, tc*64+64) of the 256x256 submatrix, in regs.
// LU with implicit partial pivoting; det = sign(perm) * prod(pivots).
__global__ __launch_bounds__(1024) void det_lu_kernel(
    const float* __restrict__ x,
    const float* __restrict__ F,
    float* __restrict__ out) {
  __shared__ float colbuf[256];   // current column k (post-update values)
  __shared__ float rowbuf[256];   // pivot row broadcast
  __shared__ int   perm[256];     // pivot row chosen at each step
  __shared__ int   upbuf[256];    // rows of submatrix (x>0 positions)
  __shared__ int   dnbuf[256];    // cols of submatrix (x<=0 positions)
  __shared__ int   wavecnt[8];
  __shared__ float partv[4];
  __shared__ int   parti[4];
  __shared__ double detacc;

  const int tid  = threadIdx.x;
  const int lane = tid & 63;
  const int w    = tid >> 6;
  const int tr   = tid & 255;
  const int tc   = tid >> 8;
  const int c0   = tc << 6;

  const float* xrow = x + (size_t)blockIdx.x * NN;

  // ---- rank the +/-1 pattern: up[] = indices with x>0, dn[] = indices x<=0
  bool pos = false;
  unsigned long long mask = 0;
  if (tid < NN) {
    float xv = xrow[tid];
    pos = xv > 0.0f;
    mask = __ballot(pos);                 // waves 0-7 fully active
    if (lane == 0) wavecnt[w] = __popcll(mask);
  }
  if (tid == 0) detacc = 1.0;
  __syncthreads();
  if (tid < NN) {
    int base = 0;
    for (int i = 0; i < w; i++) base += wavecnt[i];
    int pbelow = __popcll(mask & ((1ull << lane) - 1ull));
    if (pos) upbuf[base + pbelow] = tid;
    else     dnbuf[(64 * w - base) + (lane - pbelow)] = tid;
  }
  __syncthreads();

  // ---- gather submatrix into registers (64 elements per thread)
  const int r = upbuf[tr];
  float a[64];
#pragma unroll
  for (int j = 0; j < 64; j++) {
    int c = dnbuf[c0 + j];
    float v = 0.0f;
    if (c != r) v = F[(size_t)r * NM1 + c - (c > r ? 1 : 0)];
    a[j] = v;
  }
  bool myactive = true;
  if (tc == 0) colbuf[tr] = a[0];   // extract column 0
  __syncthreads();

  // ---- LU main loop
  for (int k = 0; k < 256; k++) {
    const int kc = k >> 6;   // retired chunk boundary

    // pivot search over active rows (waves 0-3; colbuf holds column k)
    if (tid < 256) {
      float v = myactive ? fabsf(colbuf[tid]) : -1.0f;
      int idx = tid;
#pragma unroll
      for (int off = 32; off > 0; off >>= 1) {
        float ov = __shfl_xor(v, off);
        int   oi = __shfl_xor(idx, off);
        if (ov > v) { v = ov; idx = oi; }
      }
      if (lane == 0) { partv[w] = v; parti[w] = idx; }
    }
    __syncthreads();  // B1: partials ready

    // everyone redundantly combines the 4 wave partials -> pivot p
    float bv = partv[0]; int p = parti[0];
#pragma unroll
    for (int q = 1; q < 4; q++) {
      float qv = partv[q];
      if (qv > bv) { bv = qv; p = parti[q]; }
    }
    const float piv = colbuf[p];        // broadcast LDS read
    const float invpiv = 1.0f / piv;
    if (tid == 0) { detacc *= (double)piv; perm[k] = p; }

    // pivot row broadcast (post-update register values)
    if (tr == p) {
      myactive = false;
      if (tc >= kc) {
#pragma unroll
        for (int j = 0; j < 64; j++) rowbuf[c0 + j] = a[j];
      }
    }
    // multiplier for my row (read colbuf BEFORE B2; extraction writes after)
    const float l = (myactive && tc >= kc) ? colbuf[tr] * invpiv : 0.0f;
    __syncthreads();  // B2: rowbuf ready, all colbuf reads done

    // rank-1 update of live chunks; extract column k+1 on the fly.
    if (tc >= kc) {
      const int nk  = k + 1;
      const bool extract = (tc == (nk >> 6));   // wave-uniform
      const int  nkj = nk & 63;                 // wave-uniform scalar
#pragma unroll
      for (int j = 0; j < 64; j++) {
        float u = rowbuf[c0 + j];               // wave-uniform broadcast read
        a[j] = fmaf(-l, u, a[j]);
        if (extract && j == nkj) colbuf[tr] = a[j];  // scalar-guarded
      }
    }
    __syncthreads();  // A: colbuf(k+1) ready for next search
  }

  // ---- sign of the permutation via cycle decomposition, write result
  if (tid == 0) {
    int* visited = dnbuf;  // reuse
    for (int i = 0; i < 256; i++) visited[i] = 0;
    int sign = 1;
    for (int i = 0; i < 256; i++) {
      if (!visited[i]) {
        int cnt = 0, j = i;
        while (!visited[j]) { visited[j] = 1; j = perm[j]; cnt++; }
        if ((cnt & 1) == 0) sign = -sign;   // even-length cycle flips sign
      }
    }
    out[blockIdx.x] = (float)(detacc * (double)sign);
  }
}

extern "C" void kernel_launch(void* const* d_in, const int* in_sizes, int n_in,
                              void* d_out, int out_size, void* d_ws, size_t ws_size,
                              hipStream_t stream) {
  const float* x = (const float*)d_in[0];   // (1024, 512) fp32
  const float* F = (const float*)d_in[1];   // (512*512-512,) fp32
  float* out = (float*)d_out;               // (1024,) fp32
  const int B = out_size;                   // 1024
  hipLaunchKernelGGL(det_lu_kernel, dim3(B), dim3(1024), 0, stream, x, F, out);
}

// Round 2
// 2765.777 us; speedup vs baseline: 1.4395x; 1.4395x over previous
//
#include <hip/hip_runtime.h>

#define NN 512
#define NM1 511

// One block per matrix. 1024 threads: thread (tr = tid&255, tc = tid>>8)
// owns row tr, columns [tc*64, tc*64+64) of the 256x256 submatrix, in regs.
// LU with implicit partial pivoting; det = sign(perm) * prod(pivots).
// __launch_bounds__(1024,4): 4 waves/EU -> 16 waves/CU -> 128-VGPR budget so
// a[64] stays in registers (round-1 spill: VGPR=44, matrix in scratch).
__global__ __launch_bounds__(1024, 4) void det_lu_kernel(
    const float* __restrict__ x,
    const float* __restrict__ F,
    float* __restrict__ out) {
  __shared__ __align__(16) float colbuf[256];  // column k (retired rows = 0)
  __shared__ __align__(16) float rowbuf[256];  // pivot row broadcast
  __shared__ int perm[256];                    // pivot chosen at each step
  __shared__ int upbuf[256];                   // rows (x>0 positions)
  __shared__ int dnbuf[256];                   // cols (x<=0 positions)
  __shared__ int wavecnt[8];
  __shared__ int totinv;

  const int tid  = threadIdx.x;
  const int lane = tid & 63;
  const int w    = tid >> 6;
  const int tr   = tid & 255;
  const int tc   = tid >> 8;
  const int c0   = tc << 6;

  const float* xrow = x + (size_t)blockIdx.x * NN;

  // ---- rank the +/-1 pattern
  bool pos = false;
  unsigned long long mask = 0;
  if (tid < NN) {
    float xv = xrow[tid];
    pos = xv > 0.0f;
    mask = __ballot(pos);                 // waves 0-7 fully active
    if (lane == 0) wavecnt[w] = __popcll(mask);
  }
  if (tid == 0) totinv = 0;
  __syncthreads();
  if (tid < NN) {
    int base = 0;
    for (int i = 0; i < w; i++) base += wavecnt[i];
    int pbelow = __popcll(mask & ((1ull << lane) - 1ull));
    if (pos) upbuf[base + pbelow] = tid;
    else     dnbuf[(64 * w - base) + (lane - pbelow)] = tid;
  }
  __syncthreads();

  // ---- gather submatrix into registers (64 elements per thread)
  const int r = upbuf[tr];
  float a[64];
#pragma unroll
  for (int j = 0; j < 64; j++) {
    int c = dnbuf[c0 + j];
    float v = 0.0f;
    if (c != r) v = F[(size_t)r * NM1 + c - (c > r ? 1 : 0)];
    a[j] = v;
  }
  bool myactive = true;
  double det = 1.0;
  if (tc == 0) colbuf[tr] = a[0];   // extract column 0
  __syncthreads();

  // ---- LU main loop: 2 barriers per step
  for (int k = 0; k < 256; k++) {
    const int kc = k >> 6;      // retired chunk boundary
    float l = 0.0f;
    if (tc >= kc) {             // wave-uniform: retired chunks idle to barrier
      // redundant per-wave argmax over |colbuf| (retired rows hold 0)
      unsigned key = 0u;
#pragma unroll
      for (int q = 0; q < 4; q++) {
        float v = colbuf[lane + 64 * q];
        unsigned b = __float_as_uint(fabsf(v));
        unsigned kq = (b & 0xFFFFFF00u) | (unsigned)(lane + 64 * q);
        key = key > kq ? key : kq;
      }
#pragma unroll
      for (int off = 32; off; off >>= 1) {
        unsigned o = (unsigned)__shfl_xor((int)key, off);
        key = key > o ? key : o;
      }
      const int p = (int)(key & 255u);
      const float piv = colbuf[p];        // broadcast LDS read
      det *= (double)piv;                 // redundant register tracking
      if (tid == 768) perm[k] = p;        // chunk-3 thread: never retires
      const float invpiv = 1.0f / piv;
      l = (tr == p) ? 0.0f : colbuf[tr] * invpiv;  // retired rows: colbuf==0
      if (tr == p) {
        myactive = false;
#pragma unroll
        for (int j4 = 0; j4 < 16; j4++)
          *reinterpret_cast<float4*>(&rowbuf[c0 + 4 * j4]) =
              make_float4(a[4*j4], a[4*j4+1], a[4*j4+2], a[4*j4+3]);
      }
    }
    __syncthreads();  // B: rowbuf ready; all colbuf reads of step k done

    if (tc >= kc) {
      const int nk  = k + 1;
      const bool ex = (tc == (nk >> 6));  // wave-uniform
      const int nkj = nk & 63;            // wave-uniform scalar
#pragma unroll
      for (int j4 = 0; j4 < 16; j4++) {
        const float4 u4 =
            *reinterpret_cast<const float4*>(&rowbuf[c0 + 4 * j4]);
        a[4*j4+0] = fmaf(-l, u4.x, a[4*j4+0]);
        a[4*j4+1] = fmaf(-l, u4.y, a[4*j4+1]);
        a[4*j4+2] = fmaf(-l, u4.z, a[4*j4+2]);
        a[4*j4+3] = fmaf(-l, u4.w, a[4*j4+3]);
        if (ex) {  // scalar-guarded static-index column extraction
          if (nkj == 4*j4+0) colbuf[tr] = myactive ? a[4*j4+0] : 0.0f;
          if (nkj == 4*j4+1) colbuf[tr] = myactive ? a[4*j4+1] : 0.0f;
          if (nkj == 4*j4+2) colbuf[tr] = myactive ? a[4*j4+2] : 0.0f;
          if (nkj == 4*j4+3) colbuf[tr] = myactive ? a[4*j4+3] : 0.0f;
        }
      }
    }
    __syncthreads();  // A: colbuf(k+1) ready for next search
  }

  // ---- permutation parity via parallel inversion count
  int myinv = 0;
  const int pi = perm[tr];
#pragma unroll 8
  for (int j = 0; j < 64; j++) {
    int jj = c0 + j;
    if (jj > tr && perm[jj] < pi) myinv++;
  }
#pragma unroll
  for (int off = 32; off; off >>= 1) myinv += __shfl_xor(myinv, off);
  if (lane == 0) atomicAdd(&totinv, myinv);
  __syncthreads();
  if (tid == 768) out[blockIdx.x] = (float)((totinv & 1) ? -det : det);
}

extern "C" void kernel_launch(void* const* d_in, const int* in_sizes, int n_in,
                              void* d_out, int out_size, void* d_ws, size_t ws_size,
                              hipStream_t stream) {
  const float* x = (const float*)d_in[0];   // (1024, 512) fp32
  const float* F = (const float*)d_in[1];   // (512*512-512,) fp32
  float* out = (float*)d_out;               // (1024,) fp32
  const int B = out_size;                   // 1024
  hipLaunchKernelGGL(det_lu_kernel, dim3(B), dim3(1024), 0, stream, x, F, out);
}

// Round 3
// 2390.021 us; speedup vs baseline: 1.6659x; 1.1572x over previous
//
#include <hip/hip_runtime.h>

#define NN 512
#define NM1 511
#define PCT(r, j) pcT[(r) * 13 + (j)]

// One block per matrix (1024 blocks). Blocked LU, panel r=8, implicit partial
// pivoting. Thread tile: rows {L,L+64,L+128,L+192} x cols [16w,16w+16) in regs
// (at[4][16]). Row-threads = tid>=768 (r = tid-768) run the panel column-steps
// with the panel row cached in regs (pcrow[8]). One barrier per column-step;
// rank-8 trailing update amortizes LDS broadcasts and barriers.
__global__ __launch_bounds__(1024, 4) void det_lu_kernel(
    const float* __restrict__ x,
    const float* __restrict__ F,
    float* __restrict__ out) {
  __shared__ __align__(16) float pcT[256 * 13];   // panel cols, row-major pad 13
  __shared__ __align__(16) float lbuf[8 * 256];   // multipliers per step
  __shared__ __align__(16) float Ubuf[8 * 260];   // final pivot rows (pad 260)
  __shared__ __align__(16) float araw[8 * 260];   // raw pivot rows
  __shared__ float livef[256];
  __shared__ int   perm[256];
  __shared__ int   upbuf[256];
  __shared__ int   dnbuf[256];
  __shared__ int   wavecnt[8];
  __shared__ int   totinv;

  const int tid = threadIdx.x;
  const int L   = tid & 63;       // lane
  const int w   = tid >> 6;       // wave

  const float* xrow = x + (size_t)blockIdx.x * NN;

  // ---- rank the +/-1 pattern: up = x>0 positions, dn = x<=0 positions
  bool pos = false;
  unsigned long long mask = 0;
  if (tid < NN) {
    float xv = xrow[tid];
    pos = xv > 0.0f;
    mask = __ballot(pos);
    if (L == 0) wavecnt[w] = __popcll(mask);
  }
  if (tid == 0) totinv = 0;
  if (tid < 256) livef[tid] = 1.0f;
  __syncthreads();
  if (tid < NN) {
    int base = 0;
    for (int i = 0; i < w; i++) base += wavecnt[i];
    int pbelow = __popcll(mask & ((1ull << L) - 1ull));
    if (pos) upbuf[base + pbelow] = tid;
    else     dnbuf[(64 * w - base) + (L - pbelow)] = tid;
  }
  __syncthreads();

  // ---- gather submatrix tile into registers: at[k][m] = sub[L+64k][16w+m]
  float at[4][16];
  {
    int cg[16];
#pragma unroll
    for (int m = 0; m < 16; m++) cg[m] = dnbuf[16 * w + m];
#pragma unroll
    for (int k = 0; k < 4; k++) {
      int rg = upbuf[L + 64 * k];
#pragma unroll
      for (int m = 0; m < 16; m++) {
        int c = cg[m];
        at[k][m] = (c == rg) ? 0.0f : F[(size_t)rg * NM1 + c - (c > rg ? 1 : 0)];
      }
    }
  }

  // ---- seed panel 0: wave 0 writes pcT[row][0..7] = at[k][0..7]
  if (w == 0) {
#pragma unroll
    for (int k = 0; k < 4; k++) {
      int rho = L + 64 * k;
#pragma unroll
      for (int j = 0; j < 8; j++) PCT(rho, j) = at[k][j];
    }
  }
  double det = 1.0;
  bool mylive = true;          // row-thread's own-row liveness (tid>=768)
  __syncthreads();

  // ---- panel loop
  for (int P = 0; P < 32; P++) {
    // row-threads cache their panel row in registers
    float pcrow[8];
    if (tid >= 768) {
      const int rr = tid - 768;
#pragma unroll
      for (int j = 0; j < 8; j++) pcrow[j] = PCT(rr, j);
    }

    int parr[8];
    // -------- 8 column-steps, ONE barrier each --------
#pragma unroll
    for (int s = 0; s < 8; s++) {
      // search: all threads, redundant; exclusion via register pivot history
      unsigned key = 0u;
#pragma unroll
      for (int k = 0; k < 4; k++) {
        int rho = L + 64 * k;
        float v = PCT(rho, s);
        bool excl = false;
#pragma unroll
        for (int q = 0; q < s; q++) excl |= (rho == parr[q]);
        unsigned b = __float_as_uint(fabsf(v)) & 0xFFFFFF00u;
        unsigned kq = excl ? 0u : (b | (unsigned)rho);
        key = key > kq ? key : kq;
      }
#pragma unroll
      for (int off = 32; off; off >>= 1) {
        unsigned o = (unsigned)__shfl_xor((int)key, off);
        key = key > o ? key : o;
      }
      const int p = (int)(key & 255u);
      parr[s] = p;
      const float piv = PCT(p, s);   // nobody writes col s this step
      det *= (double)piv;

      if (tid >= 768) {              // row-thread work
        const int rr = tid - 768;
        const float invp = 1.0f / piv;
        float l = (mylive && rr != p) ? pcrow[s] * invp : 0.0f;
        lbuf[s * 256 + rr] = l;
        if (rr == p) { mylive = false; livef[rr] = 0.0f; perm[P * 8 + s] = p; }
#pragma unroll
        for (int j = s + 1; j < 8; j++) {
          float uj = PCT(p, j);      // pivot row: benign same-value rewrite
          pcrow[j] = fmaf(-l, uj, pcrow[j]);
          PCT(rr, j) = pcrow[j];
        }
      }
      // raw pivot-row stash for the U-solve (live-col waves only)
      if ((2 * w + 1 > P) && L == (p & 63)) {
        const int kp = p >> 6;
#pragma unroll
        for (int kk = 0; kk < 4; kk++) if (kk == kp) {
#pragma unroll
          for (int q = 0; q < 4; q++)
            *reinterpret_cast<float4*>(&araw[s * 260 + 16 * w + 4 * q]) =
                make_float4(at[kk][4*q], at[kk][4*q+1], at[kk][4*q+2], at[kk][4*q+3]);
        }
      }
      __syncthreads();
    }

    // -------- U-solve: U[t][j] = araw[t][j] - sum_{s<t} l_s[p_t]*U[s][j]
    if (tid < 256) {
      const int j = tid;
      float u[8];
#pragma unroll
      for (int t = 0; t < 8; t++) {
        int pt = perm[P * 8 + t];
        float acc = araw[t * 260 + j];
#pragma unroll
        for (int s2 = 0; s2 < t; s2++) acc = fmaf(-lbuf[s2 * 256 + pt], u[s2], acc);
        u[t] = acc;
        Ubuf[t * 260 + j] = acc;
      }
    }
    __syncthreads();

    // -------- rank-8 trailing update + seed next panel --------
    if (2 * w + 1 > P) {
#pragma unroll
      for (int t = 0; t < 8; t++) {
        float lk[4];
#pragma unroll
        for (int k = 0; k < 4; k++) lk[k] = lbuf[t * 256 + L + 64 * k];
#pragma unroll
        for (int q = 0; q < 4; q++) {
          const float4 u4 =
              *reinterpret_cast<const float4*>(&Ubuf[t * 260 + 16 * w + 4 * q]);
#pragma unroll
          for (int k = 0; k < 4; k++) {
            at[k][4*q+0] = fmaf(-lk[k], u4.x, at[k][4*q+0]);
            at[k][4*q+1] = fmaf(-lk[k], u4.y, at[k][4*q+1]);
            at[k][4*q+2] = fmaf(-lk[k], u4.z, at[k][4*q+2]);
            at[k][4*q+3] = fmaf(-lk[k], u4.w, at[k][4*q+3]);
          }
        }
      }
    }
    {
      const int wstar = (P + 1) >> 1, h = (P + 1) & 1;
      if (P < 31 && w == wstar) {
#pragma unroll
        for (int k = 0; k < 4; k++) {
          int rho = L + 64 * k;
          float lv = livef[rho];
#pragma unroll
          for (int hh = 0; hh < 2; hh++) if (hh == h) {
#pragma unroll
            for (int j = 0; j < 8; j++) PCT(rho, j) = at[k][8 * hh + j] * lv;
          }
        }
      }
    }
    __syncthreads();
  }

  // ---- permutation parity via parallel inversion count (verified in r2)
  int myinv = 0;
  {
    const int i0 = tid & 255;
    const int cbase = (tid >> 8) * 64;
    const int pi = perm[i0];
#pragma unroll 8
    for (int j = 0; j < 64; j++) {
      int jj = cbase + j;
      if (jj > i0 && perm[jj] < pi) myinv++;
    }
  }
#pragma unroll
  for (int off = 32; off; off >>= 1) myinv += __shfl_xor(myinv, off);
  if (L == 0) atomicAdd(&totinv, myinv);
  __syncthreads();
  if (tid == 0) out[blockIdx.x] = (float)((totinv & 1) ? -det : det);
}

extern "C" void kernel_launch(void* const* d_in, const int* in_sizes, int n_in,
                              void* d_out, int out_size, void* d_ws, size_t ws_size,
                              hipStream_t stream) {
  const float* x = (const float*)d_in[0];   // (1024, 512) fp32
  const float* F = (const float*)d_in[1];   // (512*512-512,) fp32
  float* out = (float*)d_out;               // (1024,) fp32
  const int B = out_size;                   // 1024
  hipLaunchKernelGGL(det_lu_kernel, dim3(B), dim3(1024), 0, stream, x, F, out);
}